// Round 2
// baseline (759.795 us; speedup 1.0000x reference)
//
#include <hip/hip_runtime.h>
#include <math.h>

typedef _Float16 f16;
typedef _Float16 f16x8 __attribute__((ext_vector_type(8)));
typedef float f32x4 __attribute__((ext_vector_type(4)));
typedef float f32x16 __attribute__((ext_vector_type(16)));

#define NB 16
#define SS 2048
#define DD 512

// async global->LDS, 16B per lane; LDS dst must be wave-uniform base + lane*16
__device__ __forceinline__ void gl_lds16(const void* g, void* l) {
  __builtin_amdgcn_global_load_lds(
      (const __attribute__((address_space(1))) unsigned int*)g,
      (__attribute__((address_space(3))) unsigned int*)l, 16, 0, 0);
}

// ---------------- cast x (fp32) -> fp16, 8 elems/thread ----------------
__global__ __launch_bounds__(256) void cast_kernel(const float* __restrict__ x,
                                                   f16* __restrict__ o) {
  size_t i = (size_t)blockIdx.x * 256 + threadIdx.x;
  const float4* p = (const float4*)x + i * 2;
  float4 a = p[0], b = p[1];
  f16x8 v = {(f16)a.x, (f16)a.y, (f16)a.z, (f16)a.w,
             (f16)b.x, (f16)b.y, (f16)b.z, (f16)b.w};
  *((f16x8*)o + i) = v;
}

// ---------------- transpose 512x512 weight, fp32 -> fp16 ----------------
__global__ __launch_bounds__(256) void transpose_kernel(const float* __restrict__ W,
                                                        f16* __restrict__ Wt) {
  __shared__ float t[32][33];
  int bx = blockIdx.x * 32, by = blockIdx.y * 32;
  int c = threadIdx.x & 31, r0 = threadIdx.x >> 5;
  for (int r = r0; r < 32; r += 8) t[r][c] = W[(size_t)(by + r) * DD + bx + c];
  __syncthreads();
  for (int r = r0; r < 32; r += 8) Wt[(size_t)(bx + r) * DD + by + c] = (f16)t[c][r];
}

// ---------------- GEMM: C[M][N] = A[M][K=512] * Bt[N][K=512]^T ----------------
// 128x128 tile, BK=32, 4 waves (2x2 of 64x64), 16x16x32_f16 MFMA.
// Staging: tile = 128 rows x 64 B = 512 chunks of 16B; 256 lanes -> TWO
// gl_lds16 per matrix per k-step (rows 0..63, rows 64..127).  [R1 fix: was 1]
__global__ __launch_bounds__(256) void gemm_kernel(
    const f16* __restrict__ A, long sAb, const f16* __restrict__ Bt, long sBb,
    f16* __restrict__ C, long sCb, int ldc, const float* __restrict__ bias,
    int bias_row, float scale) {
  A += (size_t)blockIdx.z * sAb;
  Bt += (size_t)blockIdx.z * sBb;
  C += (size_t)blockIdx.z * sCb;
  const int m0 = blockIdx.y * 128, n0 = blockIdx.x * 128;
  __shared__ f16 Ash[128 * 32];
  __shared__ f16 Bsh[128 * 32];
  const int tid = threadIdx.x, lane = tid & 63, wave = tid >> 6;
  const int wm = wave & 1, wn = wave >> 1;
  const int l15 = lane & 15, lq = lane >> 4;  // lq = quad 0..3
  f32x4 acc[4][4] = {};
  const int srow = tid >> 2, part = tid & 3;  // staging: 4 chunks/row
  const f16* gA = A + (size_t)(m0 + srow) * DD + part * 8;
  const f16* gB = Bt + (size_t)(n0 + srow) * DD + part * 8;
  f16* lA = &Ash[tid * 8];
  f16* lB = &Bsh[tid * 8];
  for (int kt = 0; kt < 16; ++kt) {
    gl_lds16(gA + kt * 32, lA);                       // rows 0..63
    gl_lds16(gA + 64 * DD + kt * 32, lA + 2048);      // rows 64..127
    gl_lds16(gB + kt * 32, lB);
    gl_lds16(gB + 64 * DD + kt * 32, lB + 2048);
    __syncthreads();  // drains vmcnt -> LDS data visible
    f16x8 af[4], bf[4];
#pragma unroll
    for (int i = 0; i < 4; ++i)
      af[i] = *(const f16x8*)&Ash[(64 * wm + 16 * i + l15) * 32 + lq * 8];
#pragma unroll
    for (int j = 0; j < 4; ++j)
      bf[j] = *(const f16x8*)&Bsh[(64 * wn + 16 * j + l15) * 32 + lq * 8];
#pragma unroll
    for (int i = 0; i < 4; ++i)
#pragma unroll
      for (int j = 0; j < 4; ++j)
        acc[i][j] = __builtin_amdgcn_mfma_f32_16x16x32_f16(af[i], bf[j], acc[i][j], 0, 0, 0);
    __syncthreads();
  }
  // epilogue: C/D layout col=lane&15, row=(lane>>4)*4+reg  [m89-verified]
#pragma unroll
  for (int i = 0; i < 4; ++i) {
    int rb = 64 * wm + 16 * i + lq * 4;
#pragma unroll
    for (int j = 0; j < 4; ++j) {
      int cc = n0 + 64 * wn + 16 * j + l15;
#pragma unroll
      for (int r = 0; r < 4; ++r) {
        int rr = m0 + rb + r;
        float bv = bias_row ? bias[rr] : bias[cc];
        C[(size_t)rr * ldc + cc] = (f16)((acc[i][j][r] + bv) * scale);
      }
    }
  }
}

__device__ __forceinline__ float max4(float4 s) {
  return fmaxf(fmaxf(s.x, s.y), fmaxf(s.z, s.w));
}
__device__ __forceinline__ float4 expm4(float4 s, float m) {
  return make_float4(__expf(s.x - m), __expf(s.y - m), __expf(s.z - m), __expf(s.w - m));
}

// ---------------- flash attention ----------------
// Mtile=64 (q rows), Ntile=128 (k cols), 512 threads = 8 waves (wm 0..1, wn 0..3).
// 32x32x16_f16: A[m=lane&31][k=8*(lane>>5)+j], B[k=8*(lane>>5)+j][n=lane&31],
// C/D col=lane&31, row=(r&3)+8*(r>>2)+4*(lane>>5)  [m74/m101-verified]
__global__ __launch_bounds__(512, 2) void attn_kernel(
    const f16* __restrict__ Q, const f16* __restrict__ K,
    const f16* __restrict__ Vt, float* __restrict__ out) {
  const int b = blockIdx.x, qt = blockIdx.y;
  const int q0 = qt * 64;
  const int tid = threadIdx.x, lane = tid & 63, wave = tid >> 6;
  const int wm = wave >> 2, wn = wave & 3;
  const int l31 = lane & 31, lh = lane >> 5;
  __shared__ float Ssh[64][132];  // +4 pad: bank spread, keeps 16B align
  __shared__ f16 Psh[64][136];    // +8 pad
  __shared__ float red[64];       // alpha per row, then 1/l

  // persistent Q fragments (scale 1/8 pre-folded at projection)
  const f16* qp = Q + ((size_t)(b * SS + q0 + 32 * wm + l31)) * DD + lh * 8;
  f16x8 qf[32];
#pragma unroll
  for (int ks = 0; ks < 32; ++ks) qf[ks] = *(const f16x8*)(qp + ks * 16);

  f32x16 acco[4] = {};  // O rows 32*wm.., cols 128*wn..+128 (4 tiles of 32)
  const int srow = tid >> 3, sseg = tid & 7;  // softmax: 8 threads/row
  float m_i = -1e30f, l_i = 0.f;

  const f16* kbase = K + ((size_t)(b * SS + 32 * wn + l31)) * DD + lh * 8;
  const f16* vbase = Vt + ((size_t)(b * DD + 128 * wn + l31)) * SS + lh * 8;

  for (int n0 = 0; n0 < SS; n0 += 128) {
    // ---- stage 1: S(64x128) = Q Kt ----
    f32x16 sa = {};
    const f16* kp = kbase + (size_t)n0 * DD;
#pragma unroll
    for (int ks = 0; ks < 32; ++ks) {
      f16x8 kf = *(const f16x8*)(kp + ks * 16);
      sa = __builtin_amdgcn_mfma_f32_32x32x16_f16(qf[ks], kf, sa, 0, 0, 0);
    }
#pragma unroll
    for (int r = 0; r < 16; ++r) {
      int rr = (r & 3) + 8 * (r >> 2) + 4 * lh;
      Ssh[32 * wm + rr][32 * wn + l31] = sa[r];
    }
    __syncthreads();
    // ---- stage 2: online softmax (16 cols per thread) ----
    float4 s0 = *(const float4*)&Ssh[srow][sseg * 16 + 0];
    float4 s1 = *(const float4*)&Ssh[srow][sseg * 16 + 4];
    float4 s2 = *(const float4*)&Ssh[srow][sseg * 16 + 8];
    float4 s3 = *(const float4*)&Ssh[srow][sseg * 16 + 12];
    float mx = fmaxf(fmaxf(max4(s0), max4(s1)), fmaxf(max4(s2), max4(s3)));
    mx = fmaxf(mx, __shfl_xor(mx, 1));
    mx = fmaxf(mx, __shfl_xor(mx, 2));
    mx = fmaxf(mx, __shfl_xor(mx, 4));
    float m_new = fmaxf(m_i, mx);
    float4 e0 = expm4(s0, m_new), e1 = expm4(s1, m_new);
    float4 e2 = expm4(s2, m_new), e3 = expm4(s3, m_new);
    float sum = e0.x + e0.y + e0.z + e0.w + e1.x + e1.y + e1.z + e1.w +
                e2.x + e2.y + e2.z + e2.w + e3.x + e3.y + e3.z + e3.w;
    sum += __shfl_xor(sum, 1);
    sum += __shfl_xor(sum, 2);
    sum += __shfl_xor(sum, 4);
    float alpha = __expf(m_i - m_new);
    l_i = l_i * alpha + sum;
    m_i = m_new;
    if (sseg == 0) red[srow] = alpha;
    f16x8 ph0 = {(f16)e0.x, (f16)e0.y, (f16)e0.z, (f16)e0.w,
                 (f16)e1.x, (f16)e1.y, (f16)e1.z, (f16)e1.w};
    f16x8 ph1 = {(f16)e2.x, (f16)e2.y, (f16)e2.z, (f16)e2.w,
                 (f16)e3.x, (f16)e3.y, (f16)e3.z, (f16)e3.w};
    *(f16x8*)&Psh[srow][sseg * 16] = ph0;
    *(f16x8*)&Psh[srow][sseg * 16 + 8] = ph1;
    __syncthreads();
    // ---- stage 3: O = O*alpha + P V ----
    float al[16];
#pragma unroll
    for (int g = 0; g < 4; ++g) {
      float4 t4 = *(const float4*)&red[32 * wm + 8 * g + 4 * lh];
      al[4 * g + 0] = t4.x; al[4 * g + 1] = t4.y;
      al[4 * g + 2] = t4.z; al[4 * g + 3] = t4.w;
    }
#pragma unroll
    for (int t = 0; t < 4; ++t)
#pragma unroll
      for (int r = 0; r < 16; ++r) acco[t][r] *= al[4 * (r >> 2) + (r & 3)];
    const f16* vp = vbase + n0;
#pragma unroll
    for (int ks = 0; ks < 8; ++ks) {
      f16x8 pf = *(const f16x8*)&Psh[32 * wm + l31][ks * 16 + lh * 8];
#pragma unroll
      for (int t = 0; t < 4; ++t) {
        f16x8 vf = *(const f16x8*)(vp + (size_t)t * 32 * SS + ks * 16);
        acco[t] = __builtin_amdgcn_mfma_f32_32x32x16_f16(pf, vf, acco[t], 0, 0, 0);
      }
    }
    // no barrier needed: next stage1 writes Ssh only; Psh/red rewrites are
    // behind the next stage1->stage2 barrier.
  }
  __syncthreads();
  if (sseg == 0) red[srow] = 1.0f / l_i;
  __syncthreads();
  float li[16];
#pragma unroll
  for (int g = 0; g < 4; ++g) {
    float4 t4 = *(const float4*)&red[32 * wm + 8 * g + 4 * lh];
    li[4 * g + 0] = t4.x; li[4 * g + 1] = t4.y;
    li[4 * g + 2] = t4.z; li[4 * g + 3] = t4.w;
  }
  const size_t obase = ((size_t)b * SS + q0 + 32 * wm) * DD + 128 * wn + l31;
#pragma unroll
  for (int t = 0; t < 4; ++t)
#pragma unroll
    for (int r = 0; r < 16; ++r) {
      int rr = (r & 3) + 8 * (r >> 2) + 4 * lh;
      out[obase + (size_t)rr * DD + 32 * t] = acco[t][r] * li[4 * (r >> 2) + (r & 3)];
    }
}

extern "C" void kernel_launch(void* const* d_in, const int* in_sizes, int n_in,
                              void* d_out, int out_size, void* d_ws, size_t ws_size,
                              hipStream_t stream) {
  const float* x = (const float*)d_in[0];
  const float* Wq = (const float*)d_in[1];
  const float* bq = (const float*)d_in[2];
  const float* Wk = (const float*)d_in[3];
  const float* bk = (const float*)d_in[4];
  const float* Wv = (const float*)d_in[5];
  const float* bv = (const float*)d_in[6];
  float* out = (float*)d_out;
  f16* ws = (f16*)d_ws;
  const size_t NX = (size_t)NB * SS * DD;  // 16,777,216
  // ws layout (fp16 elems): xh | Q | K | Vt | WqT | WkT | WvT  => ~129.5 MB
  f16* xh = ws;
  f16* Qh = ws + NX;
  f16* Kh = ws + 2 * NX;
  f16* Vth = ws + 3 * NX;
  f16* WqT = ws + 4 * NX;
  f16* WkT = WqT + DD * DD;
  f16* WvT = WkT + DD * DD;

  cast_kernel<<<NX / 8 / 256, 256, 0, stream>>>(x, xh);
  dim3 tg(16, 16);
  transpose_kernel<<<tg, 256, 0, stream>>>(Wq, WqT);
  transpose_kernel<<<tg, 256, 0, stream>>>(Wk, WkT);
  transpose_kernel<<<tg, 256, 0, stream>>>(Wv, WvT);
  // Q = (x@Wq + bq) * 1/8   [32768,512] ; scale folded here (exact pow2)
  gemm_kernel<<<dim3(4, 256, 1), 256, 0, stream>>>(xh, 0, WqT, 0, Qh, 0, DD, bq, 0, 0.125f);
  // K = x@Wk + bk
  gemm_kernel<<<dim3(4, 256, 1), 256, 0, stream>>>(xh, 0, WkT, 0, Kh, 0, DD, bk, 0, 1.0f);
  // Vt[b][e][s] = WvT @ x[b]^T + bv[e] : M=512, N=2048, per-batch via blockIdx.z
  gemm_kernel<<<dim3(16, 4, NB), 256, 0, stream>>>(WvT, 0, xh, (long)SS * DD, Vth,
                                                   (long)DD * SS, SS, bv, 1, 1.0f);
  // attention: blockIdx.x = batch (keeps a batch's K/V on one XCD's L2)
  attn_kernel<<<dim3(NB, SS / 64), 512, 0, stream>>>(Qh, Kh, Vth, out);
}